// Round 7
// baseline (13494.673 us; speedup 1.0000x reference)
//
#include <hip/hip_runtime.h>
#include <hip/hip_cooperative_groups.h>
#include <math.h>

namespace cg = cooperative_groups;

#define NB 8
#define NN 2048
#define ND 128
#define NITER 32

// eps = blur^2 = (5e-5)^2 = 2.5e-9. All potentials stored in LOG2-scaled units:
// F2 = (f/eps)*log2e etc. M2_ij = dot_ij/eps*log2e = q_ij * S_tile(row).
#define EPS_F   2.5e-9f
#define LNEG2   (-11.0f)                                   /* log2(1/2048) */
#define HSCALE2 ((float)(0.5 * 1.4426950408889634 / 2.5e-9))
#define SK2     ((float)(1.4426950408889634 / (255.0 * 2.5e-9)))

// ---------- preprocessing ----------

// wx[d] = sum_t x[0,t,d]^2  (reference quirk: batch 0 only), same for y
__global__ __launch_bounds__(256) void k_colsum(const float* __restrict__ x,
                                                const float* __restrict__ y,
                                                float* __restrict__ wx,
                                                float* __restrict__ wy) {
    const float* in = blockIdx.y ? y : x;
    float* w = blockIdx.y ? wy : wx;
    int d = blockIdx.x;
    int t = threadIdx.x;
    float sum = 0.f;
    for (int k = t; k < NN; k += 256) {
        float v = in[(size_t)k * ND + d];
        sum += v * v;
    }
    for (int off = 32; off > 0; off >>= 1) sum += __shfl_down(sum, off);
    __shared__ float ls[4];
    if ((t & 63) == 0) ls[t >> 6] = sum;
    __syncthreads();
    if (t == 0) w[d] = ls[0] + ls[1] + ls[2] + ls[3];
}

// X2 = x^2 / wx; h2 = 0.5*|X2 row|^2/eps*log2e
__global__ __launch_bounds__(128) void k_norm(const float* __restrict__ x,
                                              const float* __restrict__ y,
                                              const float* __restrict__ wx,
                                              const float* __restrict__ wy,
                                              float* __restrict__ X2,
                                              float* __restrict__ Y2,
                                              float* __restrict__ hx,
                                              float* __restrict__ hy) {
    int gx = blockIdx.x;                 // b*NN + i
    const float* in = blockIdx.y ? y : x;
    const float* w  = blockIdx.y ? wy : wx;
    float* o  = blockIdx.y ? Y2 : X2;
    float* h  = blockIdx.y ? hy : hx;
    int d = threadIdx.x;
    size_t base = (size_t)gx * ND;
    float v = in[base + d];
    float v2 = (v * v) / w[d];
    o[base + d] = v2;
    float sq = v2 * v2;
    for (int off = 32; off > 0; off >>= 1) sq += __shfl_down(sq, off);
    __shared__ float ls[2];
    if ((d & 63) == 0) ls[d >> 6] = sq;
    __syncthreads();
    if (d == 0) h[gx] = (ls[0] + ls[1]) * HSCALE2;
}

__global__ __launch_bounds__(256) void k_init(const float* __restrict__ hx,
                                              const float* __restrict__ hy,
                                              float* __restrict__ Gt,
                                              float* __restrict__ Px, float* __restrict__ Pax,
                                              float* __restrict__ Py, float* __restrict__ Pay) {
    int tid = blockIdx.x * 256 + threadIdx.x;
    Gt[tid]  = LNEG2 - hy[tid];
    Px[tid]  = 0.f;
    Py[tid]  = 0.f;
    Pax[tid] = LNEG2 - hx[tid];
    Pay[tid] = LNEG2 - hy[tid];
}

__device__ __forceinline__ unsigned int pack4q(const float* a, float iv) {
    int q0 = (int)fmaf(a[0], iv, 0.5f); q0 = q0 > 255 ? 255 : q0;
    int q1 = (int)fmaf(a[1], iv, 0.5f); q1 = q1 > 255 ? 255 : q1;
    int q2 = (int)fmaf(a[2], iv, 0.5f); q2 = q2 > 255 ? 255 : q2;
    int q3 = (int)fmaf(a[3], iv, 0.5f); q3 = q3 > 255 ? 255 : q3;
    return (unsigned int)q0 | ((unsigned int)q1 << 8) | ((unsigned int)q2 << 16) | ((unsigned int)q3 << 24);
}

// ---------- GEMM + per-(row,128-col-tile) max quantization ----------
// LDS: As/Bs (33 KB) reused for the epilogue T/sinv buffers (they are dead
// after the K-loop) -> 33.8 KB total -> 4 blocks/CU.
template<bool DO_T>
__global__ __launch_bounds__(256, 4) void k_gemm(const float* __restrict__ A,
                                                 const float* __restrict__ B,
                                                 float* __restrict__ Srow,
                                                 float* __restrict__ Scol,
                                                 unsigned char* __restrict__ C,
                                                 unsigned char* __restrict__ Ct,
                                                 int b0) {
    __shared__ __align__(16) char smem[33792];
    float (*As)[132] = (float (*)[132])smem;                     // 16896 B
    float (*Bs)[132] = (float (*)[132])(smem + 16896);           // 16896 B
    unsigned char (*T)[144] = (unsigned char (*)[144])smem;      // 18432 B (epilogue)
    float* sinv = (float*)(smem + 18432);                        // 512 B (epilogue)
    int bi = blockIdx.x, bj = blockIdx.y, bz = blockIdx.z;
    size_t bg = (size_t)(b0 + bz);
    const float* Ab = A + (bg * NN + (size_t)bi * 128) * ND;
    const float* Bb = B + (bg * NN + (size_t)bj * 128) * ND;
    int t = threadIdx.x;
    int tx = t & 15, ty = t >> 4;
    float acc[8][8];
#pragma unroll
    for (int i = 0; i < 8; ++i)
#pragma unroll
        for (int j = 0; j < 8; ++j) acc[i][j] = 0.f;
    int lr = t >> 3;            // 0..31
    int kq = (t & 7) << 2;      // k-quad
    for (int kt = 0; kt < ND; kt += 32) {
        __syncthreads();
#pragma unroll
        for (int s2 = 0; s2 < 4; ++s2) {
            int r = lr + (s2 << 5);
            float4 av = *(const float4*)(Ab + (size_t)r * ND + kt + kq);
            As[kq + 0][r] = av.x; As[kq + 1][r] = av.y; As[kq + 2][r] = av.z; As[kq + 3][r] = av.w;
            float4 bv = *(const float4*)(Bb + (size_t)r * ND + kt + kq);
            Bs[kq + 0][r] = bv.x; Bs[kq + 1][r] = bv.y; Bs[kq + 2][r] = bv.z; Bs[kq + 3][r] = bv.w;
        }
        __syncthreads();
#pragma unroll
        for (int k = 0; k < 32; ++k) {
            float a[8], bb[8];
            *(float4*)(a + 0)  = *(const float4*)&As[k][4 * ty];
            *(float4*)(a + 4)  = *(const float4*)&As[k][64 + 4 * ty];
            *(float4*)(bb + 0) = *(const float4*)&Bs[k][4 * tx];
            *(float4*)(bb + 4) = *(const float4*)&Bs[k][64 + 4 * tx];
#pragma unroll
            for (int i = 0; i < 8; ++i)
#pragma unroll
                for (int j = 0; j < 8; ++j)
                    acc[i][j] = fmaf(a[i], bb[j], acc[i][j]);
        }
    }
    // ---- row-tile maxes (shuffle across the 16 tx lanes) + pack pass 1 ----
    float inv_r[8];
#pragma unroll
    for (int i = 0; i < 8; ++i) {
        float m0 = fmaxf(fmaxf(fmaxf(acc[i][0], acc[i][1]), fmaxf(acc[i][2], acc[i][3])),
                         fmaxf(fmaxf(acc[i][4], acc[i][5]), fmaxf(acc[i][6], acc[i][7])));
#pragma unroll
        for (int off = 1; off <= 8; off <<= 1) m0 = fmaxf(m0, __shfl_xor(m0, off));
        m0 = fmaxf(m0, 1e-30f);
        inv_r[i] = 255.f / m0;
        if (tx == 0) {
            int m = ((i & 4) << 4) + 4 * ty + (i & 3);
            Srow[(bg * NN + (size_t)bi * 128 + m) * 16 + bj] = m0 * SK2;
        }
    }
    __syncthreads();        // As/Bs dead from here; T aliases them
#pragma unroll
    for (int i = 0; i < 8; ++i) {
        int m = ((i & 4) << 4) + 4 * ty + (i & 3);
        *(unsigned int*)&T[m][4 * tx]      = pack4q(&acc[i][0], inv_r[i]);
        *(unsigned int*)&T[m][64 + 4 * tx] = pack4q(&acc[i][4], inv_r[i]);
    }
    __syncthreads();
    {
        int r = t >> 1, hf = t & 1;
        size_t grow = (size_t)bz * NN + (size_t)bi * 128 + r;
        unsigned char* dst = C + grow * NN + (size_t)bj * 128 + 64 * hf;
        const uint4* src = (const uint4*)&T[r][64 * hf];
        uint4 v0 = src[0], v1 = src[1], v2 = src[2], v3 = src[3];
        *(uint4*)(dst + 0)  = v0;
        *(uint4*)(dst + 16) = v1;
        *(uint4*)(dst + 32) = v2;
        *(uint4*)(dst + 48) = v3;
    }
    if (DO_T) {
        __syncthreads();                    // T stores consumed; reuse as col-max buffer
        float* CMf = (float*)smem;          // 16 x 128 floats (8 KB)
#pragma unroll
        for (int j = 0; j < 8; ++j) {
            float cm = acc[0][j];
#pragma unroll
            for (int i = 1; i < 8; ++i) cm = fmaxf(cm, acc[i][j]);
            int jl = (j < 4) ? (4 * tx + j) : (60 + 4 * tx + j);
            CMf[ty * 128 + jl] = cm;
        }
        __syncthreads();
        if (t < 128) {
            float cm = CMf[t];
#pragma unroll
            for (int k = 1; k < 16; ++k) cm = fmaxf(cm, CMf[k * 128 + t]);
            cm = fmaxf(cm, 1e-30f);
            Scol[(bg * NN + (size_t)bj * 128 + t) * 16 + bi] = cm * SK2;
            sinv[t] = 255.f / cm;
        }
        __syncthreads();
#pragma unroll
        for (int i = 0; i < 8; ++i) {
            int m = ((i & 4) << 4) + 4 * ty + (i & 3);
#pragma unroll
            for (int j = 0; j < 8; ++j) {
                int jl = (j < 4) ? (4 * tx + j) : (60 + 4 * tx + j);
                int q = (int)fmaf(acc[i][j], sinv[jl], 0.5f);
                T[jl][m] = (unsigned char)(q > 255 ? 255 : q);
            }
        }
        __syncthreads();
        {
            int r = t >> 1, hf = t & 1;
            size_t grow = (size_t)bz * NN + (size_t)bj * 128 + r;
            unsigned char* dst = Ct + grow * NN + (size_t)bi * 128 + 64 * hf;
            const uint4* src = (const uint4*)&T[r][64 * hf];
            uint4 v0 = src[0], v1 = src[1], v2 = src[2], v3 = src[3];
            *(uint4*)(dst + 0)  = v0;
            *(uint4*)(dst + 16) = v1;
            *(uint4*)(dst + 32) = v2;
            *(uint4*)(dst + 48) = v3;
        }
    }
}

// ---------- Sinkhorn iteration phase (shared by coop + fallback kernels) ----------
struct SArgs {
    const unsigned char *Qxy, *Qyx, *Qxx, *Qyy;   // group-relative [G][2048][2048]
    const float *Sxy, *Syx, *Sxx, *Syy;           // global [NB*NN*16]
    float *Fa, *Gt, *Px, *Py;                     // global [NB*NN]
    float *PaxA, *PaxB, *PayA, *PayB;             // global [NB*NN]
    const float *hx, *hy;                         // global [NB*NN]
    int b0;                                       // batch base of this group
};

// Grid decode: nblk blocks, half 0 = lse pass (f/g), half 1 = sym pass.
// Per half: 2^bshift blocks per batch, (2048>>bshift) rows/block, /4 per wave.
__device__ __forceinline__ void sink_phase(const SArgs& a, int bid, int nblk,
                                           int cur, int ph, float* vs, int bshift) {
    int half = nblk >> 1;
    int mh = bid >= half;
    int rem = mh ? bid - half : bid;
    int brel = rem >> bshift;
    int rb = rem & ((1 << bshift) - 1);
    int rpb = NN >> bshift;            // rows per block
    int rpw = rpb >> 2;                // rows per wave
    int r0 = rb * rpb;
    int t = threadIdx.x;
    int w = t >> 6, l = t & 63;
    size_t bg = (size_t)(a.b0 + brel);
    size_t gx0 = (bg << 11) + r0 + w * rpw;                       // global row base (this wave)
    size_t qbase = ((((size_t)brel << 11) + r0 + w * rpw) << 11); // group-relative Q offset

    const unsigned char* Q;
    const float* S;
    const float* v;
    float* Pa_w = nullptr;
    const float* hp = nullptr;
    float* Pp = nullptr;
    if (ph == 0) {
        if (mh == 0) { Q = a.Qxy; S = a.Sxy; v = a.Gt + (bg << 11); }
        else { Q = a.Qxx; S = a.Sxx; v = (cur ? a.PaxB : a.PaxA) + (bg << 11);
               Pa_w = cur ? a.PaxA : a.PaxB; hp = a.hx; Pp = a.Px; }
    } else {
        if (mh == 0) { Q = a.Qyx; S = a.Syx; v = a.Fa + (bg << 11); }
        else { Q = a.Qyy; S = a.Syy; v = (cur ? a.PayB : a.PayA) + (bg << 11);
               Pa_w = cur ? a.PayA : a.PayB; hp = a.hy; Pp = a.Py; }
    }
    float* out0 = (ph == 0) ? a.Fa : a.Gt;

    // stage v into LDS with XOR swizzle (breaks 128B-stride bank conflict)
    {
        const float4* gv = (const float4*)v;
        float4 a0 = gv[2 * t], a1 = gv[2 * t + 1];
        int B0 = t << 5;
        int sw = ((t >> 2) & 7) << 4;
        *(float4*)((char*)vs + (B0 ^ sw)) = a0;
        *(float4*)((char*)vs + ((B0 + 16) ^ sw)) = a1;
    }
    __syncthreads();
    float vv[32];
#pragma unroll
    for (int u = 0; u < 8; ++u) {
        int B = ((l << 7) + (u << 4)) ^ ((l & 7) << 4);
        *(float4*)&vv[u * 4] = *(const float4*)((char*)vs + B);
    }

    const unsigned char* rp0 = Q + qbase + ((size_t)l << 5);
    uint4 qa = *(const uint4*)rp0;
    uint4 qb = *(const uint4*)(rp0 + 16);
    float sc = S[(gx0 << 4) + (l >> 2)];
#pragma unroll 1
    for (int r = 0; r < rpw; ++r) {
        uint4 na, nb2; float nsc;
        if (r < rpw - 1) {
            const unsigned char* np = rp0 + ((size_t)(r + 1) << 11);
            na = *(const uint4*)np;
            nb2 = *(const uint4*)(np + 16);
            nsc = S[((gx0 + r + 1) << 4) + (l >> 2)];
        }
        unsigned int qs[8] = {qa.x, qa.y, qa.z, qa.w, qb.x, qb.y, qb.z, qb.w};
        float m0 = -INFINITY, m1 = -INFINITY, m2 = -INFINITY, m3 = -INFINITY;
#pragma unroll
        for (int u = 0; u < 8; ++u) {
            unsigned int q = qs[u];
            m0 = fmaxf(m0, fmaf((float)(unsigned char)(q      ), sc, vv[4 * u + 0]));
            m1 = fmaxf(m1, fmaf((float)(unsigned char)(q >>  8), sc, vv[4 * u + 1]));
            m2 = fmaxf(m2, fmaf((float)(unsigned char)(q >> 16), sc, vv[4 * u + 2]));
            m3 = fmaxf(m3, fmaf((float)(q >> 24),                sc, vv[4 * u + 3]));
        }
        float mx = fmaxf(fmaxf(m0, m1), fmaxf(m2, m3));
#pragma unroll
        for (int off = 32; off; off >>= 1) mx = fmaxf(mx, __shfl_xor(mx, off));
        float s0 = 0.f, s1 = 0.f, s2 = 0.f, s3 = 0.f;
#pragma unroll
        for (int u = 0; u < 8; ++u) {
            unsigned int q = qs[u];
            s0 += __builtin_amdgcn_exp2f(fmaf((float)(unsigned char)(q      ), sc, vv[4 * u + 0]) - mx);
            s1 += __builtin_amdgcn_exp2f(fmaf((float)(unsigned char)(q >>  8), sc, vv[4 * u + 1]) - mx);
            s2 += __builtin_amdgcn_exp2f(fmaf((float)(unsigned char)(q >> 16), sc, vv[4 * u + 2]) - mx);
            s3 += __builtin_amdgcn_exp2f(fmaf((float)(q >> 24),                sc, vv[4 * u + 3]) - mx);
        }
        float ss = (s0 + s1) + (s2 + s3);
#pragma unroll
        for (int off = 32; off; off >>= 1) ss += __shfl_xor(ss, off);
        if (l == 0) {
            size_t gx = gx0 + r;
            float lse2 = mx + log2f(ss);
            if (mh == 0) {
                out0[gx] = LNEG2 - lse2;
            } else {
                float pn = 0.5f * (Pp[gx] + hp[gx] - lse2);
                Pp[gx] = pn;
                Pa_w[gx] = LNEG2 + pn - hp[gx];
            }
        }
        qa = na; qb = nb2; sc = nsc;
    }
}

__global__ __launch_bounds__(256, 8) void k_sink(SArgs a, int bshift) {
    cg::grid_group grid = cg::this_grid();
    __shared__ __align__(16) float vs[2048];
    int cur = 0;
    for (int it = 0; it < NITER; ++it) {
        sink_phase(a, blockIdx.x, gridDim.x, cur, 0, vs, bshift);
        grid.sync();
        sink_phase(a, blockIdx.x, gridDim.x, cur, 1, vs, bshift);
        grid.sync();
        cur ^= 1;
    }
}

// Fallback: one phase per launch (inter-launch sync replaces grid.sync)
__global__ __launch_bounds__(256, 8) void k_step(SArgs a, int cur, int ph, int bshift) {
    __shared__ __align__(16) float vs[2048];
    sink_phase(a, blockIdx.x, gridDim.x, cur, ph, vs, bshift);
}

// ---------- final reduction (log2 domain -> natural) ----------
__global__ __launch_bounds__(256) void k_final(const float* __restrict__ Fa, const float* __restrict__ Gt,
                                               const float* __restrict__ Px, const float* __restrict__ Py,
                                               const float* __restrict__ hx, const float* __restrict__ hy,
                                               float* __restrict__ out) {
    int t = threadIdx.x;
    double acc = 0.0;
    for (int i = t; i < NB * NN; i += 256) {
        acc += (double)(Fa[i] + hx[i]) + (double)(Gt[i] + hy[i])
             - (double)Px[i] - (double)Py[i];
    }
    __shared__ double ld[256];
    ld[t] = acc;
    __syncthreads();
    for (int off = 128; off > 0; off >>= 1) {
        if (t < off) ld[t] += ld[t + off];
        __syncthreads();
    }
    if (t == 0) {
        double total = ld[0] - 2.0 * (double)LNEG2 * (double)(NB * NN);
        out[0] = (float)((double)EPS_F * 0.6931471805599453 * total / (double)NN);
    }
}

extern "C" void kernel_launch(void* const* d_in, const int* in_sizes, int n_in,
                              void* d_out, int out_size, void* d_ws, size_t ws_size,
                              hipStream_t stream) {
    (void)in_sizes; (void)n_in; (void)out_size;
    const float* x = (const float*)d_in[0];
    const float* y = (const float*)d_in[1];
    float* out = (float*)d_out;

    char* ws = (char*)d_ws;
    size_t off = 0;
    auto alloc = [&](size_t bytes) -> char* {
        char* p = ws + off;
        off += (bytes + 255) & ~(size_t)255;
        return p;
    };

    float* X2 = (float*)alloc((size_t)NB * NN * ND * 4);
    float* Y2 = (float*)alloc((size_t)NB * NN * ND * 4);
    float* wx = (float*)alloc(ND * 4);
    float* wy = (float*)alloc(ND * 4);
    float* hx = (float*)alloc((size_t)NB * NN * 4);
    float* hy = (float*)alloc((size_t)NB * NN * 4);
    float* Fa = (float*)alloc((size_t)NB * NN * 4);
    float* Gt = (float*)alloc((size_t)NB * NN * 4);
    float* Px = (float*)alloc((size_t)NB * NN * 4);
    float* Py = (float*)alloc((size_t)NB * NN * 4);
    float* PaxA = (float*)alloc((size_t)NB * NN * 4);
    float* PaxB = (float*)alloc((size_t)NB * NN * 4);
    float* PayA = (float*)alloc((size_t)NB * NN * 4);
    float* PayB = (float*)alloc((size_t)NB * NN * 4);
    float* Sxy = (float*)alloc((size_t)NB * NN * 16 * 4);
    float* Syx = (float*)alloc((size_t)NB * NN * 16 * 4);
    float* Sxx = (float*)alloc((size_t)NB * NN * 16 * 4);
    float* Syy = (float*)alloc((size_t)NB * NN * 16 * 4);

    // Q matrices: 4 * 4MB per batch in group; shrink group if workspace is small
    size_t small_end = off;
    size_t matBytes = (size_t)NN * NN;               // 4 MB (u8)
    int G = NB;
    while (G > 1 && small_end + 4 * matBytes * (size_t)G + 4096 > ws_size) G >>= 1;
    unsigned char* Qxy = (unsigned char*)alloc(matBytes * (size_t)G);
    unsigned char* Qyx = (unsigned char*)alloc(matBytes * (size_t)G);
    unsigned char* Qxx = (unsigned char*)alloc(matBytes * (size_t)G);
    unsigned char* Qyy = (unsigned char*)alloc(matBytes * (size_t)G);

    // Size the cooperative grid to full co-residency (host-side queries are
    // deterministic and graph-capture-safe). bshift: blocks-per-batch = 2^bshift.
    int maxB = 0;
    if (hipOccupancyMaxActiveBlocksPerMultiprocessor(&maxB, reinterpret_cast<const void*>(&k_sink),
                                                     256, 0) != hipSuccess) maxB = 0;
    int ncu = 0;
    if (hipDeviceGetAttribute(&ncu, hipDeviceAttributeMultiprocessorCount, 0) != hipSuccess || ncu <= 0)
        ncu = 256;
    long cap = (long)maxB * (long)ncu;
    int bshift = 5;                                   // 64*G blocks (round-5 baseline)
    while (bshift < 7 && (long)(2 * G << (bshift + 1)) <= cap) ++bshift;
    int nblk = 2 * G << bshift;

    k_colsum<<<dim3(ND, 2), 256, 0, stream>>>(x, y, wx, wy);
    k_norm<<<dim3(NB * NN, 2), 128, 0, stream>>>(x, y, wx, wy, X2, Y2, hx, hy);
    k_init<<<dim3(NB * NN / 256), 256, 0, stream>>>(hx, hy, Gt, Px, PaxA, Py, PayA);

    for (int b0 = 0; b0 < NB; b0 += G) {
        k_gemm<true><<<dim3(16, 16, G), 256, 0, stream>>>(X2, Y2, Sxy, Syx, Qxy, Qyx, b0);
        k_gemm<false><<<dim3(16, 16, G), 256, 0, stream>>>(X2, X2, Sxx, nullptr, Qxx, nullptr, b0);
        k_gemm<false><<<dim3(16, 16, G), 256, 0, stream>>>(Y2, Y2, Syy, nullptr, Qyy, nullptr, b0);

        SArgs sa;
        sa.Qxy = Qxy; sa.Qyx = Qyx; sa.Qxx = Qxx; sa.Qyy = Qyy;
        sa.Sxy = Sxy; sa.Syx = Syx; sa.Sxx = Sxx; sa.Syy = Syy;
        sa.Fa = Fa; sa.Gt = Gt; sa.Px = Px; sa.Py = Py;
        sa.PaxA = PaxA; sa.PaxB = PaxB; sa.PayA = PayA; sa.PayB = PayB;
        sa.hx = hx; sa.hy = hy; sa.b0 = b0;
        void* kargs[] = { &sa, &bshift };
        hipError_t e = hipLaunchCooperativeKernel((void*)k_sink, dim3(nblk), dim3(256),
                                                  kargs, 0, stream);
        if (e != hipSuccess) {
            // fallback: per-phase launches (inter-launch sync replaces grid.sync)
            (void)hipGetLastError();   // clear the error state
            int cur = 0;
            for (int it = 0; it < NITER; ++it) {
                k_step<<<dim3(nblk), 256, 0, stream>>>(sa, cur, 0, bshift);
                k_step<<<dim3(nblk), 256, 0, stream>>>(sa, cur, 1, bshift);
                cur ^= 1;
            }
        }
    }
    k_final<<<dim3(1), 256, 0, stream>>>(Fa, Gt, Px, Py, hx, hy, out);
}

// Round 8
// 4896.877 us; speedup vs baseline: 2.7558x; 2.7558x over previous
//
#include <hip/hip_runtime.h>
#include <hip/hip_cooperative_groups.h>
#include <math.h>

namespace cg = cooperative_groups;

#define NB 8
#define NN 2048
#define ND 128
#define NITER 32

// eps = blur^2 = (5e-5)^2 = 2.5e-9. All potentials stored in LOG2-scaled units:
// F2 = (f/eps)*log2e etc. M2_ij = dot_ij/eps*log2e = q_ij * S_tile(row).
#define EPS_F   2.5e-9f
#define LNEG2   (-11.0f)                                   /* log2(1/2048) */
#define HSCALE2 ((float)(0.5 * 1.4426950408889634 / 2.5e-9))
#define SK2     ((float)(1.4426950408889634 / (255.0 * 2.5e-9)))

// ---------- preprocessing ----------

// wx[d] = sum_t x[0,t,d]^2  (reference quirk: batch 0 only), same for y
__global__ __launch_bounds__(256) void k_colsum(const float* __restrict__ x,
                                                const float* __restrict__ y,
                                                float* __restrict__ wx,
                                                float* __restrict__ wy) {
    const float* in = blockIdx.y ? y : x;
    float* w = blockIdx.y ? wy : wx;
    int d = blockIdx.x;
    int t = threadIdx.x;
    float sum = 0.f;
    for (int k = t; k < NN; k += 256) {
        float v = in[(size_t)k * ND + d];
        sum += v * v;
    }
    for (int off = 32; off > 0; off >>= 1) sum += __shfl_down(sum, off);
    __shared__ float ls[4];
    if ((t & 63) == 0) ls[t >> 6] = sum;
    __syncthreads();
    if (t == 0) w[d] = ls[0] + ls[1] + ls[2] + ls[3];
}

// X2 = x^2 / wx; h2 = 0.5*|X2 row|^2/eps*log2e
__global__ __launch_bounds__(128) void k_norm(const float* __restrict__ x,
                                              const float* __restrict__ y,
                                              const float* __restrict__ wx,
                                              const float* __restrict__ wy,
                                              float* __restrict__ X2,
                                              float* __restrict__ Y2,
                                              float* __restrict__ hx,
                                              float* __restrict__ hy) {
    int gx = blockIdx.x;                 // b*NN + i
    const float* in = blockIdx.y ? y : x;
    const float* w  = blockIdx.y ? wy : wx;
    float* o  = blockIdx.y ? Y2 : X2;
    float* h  = blockIdx.y ? hy : hx;
    int d = threadIdx.x;
    size_t base = (size_t)gx * ND;
    float v = in[base + d];
    float v2 = (v * v) / w[d];
    o[base + d] = v2;
    float sq = v2 * v2;
    for (int off = 32; off > 0; off >>= 1) sq += __shfl_down(sq, off);
    __shared__ float ls[2];
    if ((d & 63) == 0) ls[d >> 6] = sq;
    __syncthreads();
    if (d == 0) h[gx] = (ls[0] + ls[1]) * HSCALE2;
}

__global__ __launch_bounds__(256) void k_init(const float* __restrict__ hx,
                                              const float* __restrict__ hy,
                                              float* __restrict__ Gt,
                                              float* __restrict__ Px, float* __restrict__ Pax,
                                              float* __restrict__ Py, float* __restrict__ Pay) {
    int tid = blockIdx.x * 256 + threadIdx.x;
    Gt[tid]  = LNEG2 - hy[tid];
    Px[tid]  = 0.f;
    Py[tid]  = 0.f;
    Pax[tid] = LNEG2 - hx[tid];
    Pay[tid] = LNEG2 - hy[tid];
}

__device__ __forceinline__ unsigned int pack4q(const float* a, float iv) {
    int q0 = (int)fmaf(a[0], iv, 0.5f); q0 = q0 > 255 ? 255 : q0;
    int q1 = (int)fmaf(a[1], iv, 0.5f); q1 = q1 > 255 ? 255 : q1;
    int q2 = (int)fmaf(a[2], iv, 0.5f); q2 = q2 > 255 ? 255 : q2;
    int q3 = (int)fmaf(a[3], iv, 0.5f); q3 = q3 > 255 ? 255 : q3;
    return (unsigned int)q0 | ((unsigned int)q1 << 8) | ((unsigned int)q2 << 16) | ((unsigned int)q3 << 24);
}

// ---------- GEMM + per-(row,128-col-tile) max quantization ----------
// LDS: As/Bs (33 KB) reused for the epilogue T/sinv buffers (they are dead
// after the K-loop) -> 33.8 KB total -> 4 blocks/CU.
template<bool DO_T>
__global__ __launch_bounds__(256, 4) void k_gemm(const float* __restrict__ A,
                                                 const float* __restrict__ B,
                                                 float* __restrict__ Srow,
                                                 float* __restrict__ Scol,
                                                 unsigned char* __restrict__ C,
                                                 unsigned char* __restrict__ Ct,
                                                 int b0) {
    __shared__ __align__(16) char smem[33792];
    float (*As)[132] = (float (*)[132])smem;                     // 16896 B
    float (*Bs)[132] = (float (*)[132])(smem + 16896);           // 16896 B
    unsigned char (*T)[144] = (unsigned char (*)[144])smem;      // 18432 B (epilogue)
    float* sinv = (float*)(smem + 18432);                        // 512 B (epilogue)
    int bi = blockIdx.x, bj = blockIdx.y, bz = blockIdx.z;
    size_t bg = (size_t)(b0 + bz);
    const float* Ab = A + (bg * NN + (size_t)bi * 128) * ND;
    const float* Bb = B + (bg * NN + (size_t)bj * 128) * ND;
    int t = threadIdx.x;
    int tx = t & 15, ty = t >> 4;
    float acc[8][8];
#pragma unroll
    for (int i = 0; i < 8; ++i)
#pragma unroll
        for (int j = 0; j < 8; ++j) acc[i][j] = 0.f;
    int lr = t >> 3;            // 0..31
    int kq = (t & 7) << 2;      // k-quad
    for (int kt = 0; kt < ND; kt += 32) {
        __syncthreads();
#pragma unroll
        for (int s2 = 0; s2 < 4; ++s2) {
            int r = lr + (s2 << 5);
            float4 av = *(const float4*)(Ab + (size_t)r * ND + kt + kq);
            As[kq + 0][r] = av.x; As[kq + 1][r] = av.y; As[kq + 2][r] = av.z; As[kq + 3][r] = av.w;
            float4 bv = *(const float4*)(Bb + (size_t)r * ND + kt + kq);
            Bs[kq + 0][r] = bv.x; Bs[kq + 1][r] = bv.y; Bs[kq + 2][r] = bv.z; Bs[kq + 3][r] = bv.w;
        }
        __syncthreads();
#pragma unroll
        for (int k = 0; k < 32; ++k) {
            float a[8], bb[8];
            *(float4*)(a + 0)  = *(const float4*)&As[k][4 * ty];
            *(float4*)(a + 4)  = *(const float4*)&As[k][64 + 4 * ty];
            *(float4*)(bb + 0) = *(const float4*)&Bs[k][4 * tx];
            *(float4*)(bb + 4) = *(const float4*)&Bs[k][64 + 4 * tx];
#pragma unroll
            for (int i = 0; i < 8; ++i)
#pragma unroll
                for (int j = 0; j < 8; ++j)
                    acc[i][j] = fmaf(a[i], bb[j], acc[i][j]);
        }
    }
    // ---- row-tile maxes (shuffle across the 16 tx lanes) + pack pass 1 ----
    float inv_r[8];
#pragma unroll
    for (int i = 0; i < 8; ++i) {
        float m0 = fmaxf(fmaxf(fmaxf(acc[i][0], acc[i][1]), fmaxf(acc[i][2], acc[i][3])),
                         fmaxf(fmaxf(acc[i][4], acc[i][5]), fmaxf(acc[i][6], acc[i][7])));
#pragma unroll
        for (int off = 1; off <= 8; off <<= 1) m0 = fmaxf(m0, __shfl_xor(m0, off));
        m0 = fmaxf(m0, 1e-30f);
        inv_r[i] = 255.f / m0;
        if (tx == 0) {
            int m = ((i & 4) << 4) + 4 * ty + (i & 3);
            Srow[(bg * NN + (size_t)bi * 128 + m) * 16 + bj] = m0 * SK2;
        }
    }
    __syncthreads();        // As/Bs dead from here; T aliases them
#pragma unroll
    for (int i = 0; i < 8; ++i) {
        int m = ((i & 4) << 4) + 4 * ty + (i & 3);
        *(unsigned int*)&T[m][4 * tx]      = pack4q(&acc[i][0], inv_r[i]);
        *(unsigned int*)&T[m][64 + 4 * tx] = pack4q(&acc[i][4], inv_r[i]);
    }
    __syncthreads();
    {
        int r = t >> 1, hf = t & 1;
        size_t grow = (size_t)bz * NN + (size_t)bi * 128 + r;
        unsigned char* dst = C + grow * NN + (size_t)bj * 128 + 64 * hf;
        const uint4* src = (const uint4*)&T[r][64 * hf];
        uint4 v0 = src[0], v1 = src[1], v2 = src[2], v3 = src[3];
        *(uint4*)(dst + 0)  = v0;
        *(uint4*)(dst + 16) = v1;
        *(uint4*)(dst + 32) = v2;
        *(uint4*)(dst + 48) = v3;
    }
    if (DO_T) {
        __syncthreads();                    // T stores consumed; reuse as col-max buffer
        float* CMf = (float*)smem;          // 16 x 128 floats (8 KB)
#pragma unroll
        for (int j = 0; j < 8; ++j) {
            float cm = acc[0][j];
#pragma unroll
            for (int i = 1; i < 8; ++i) cm = fmaxf(cm, acc[i][j]);
            int jl = (j < 4) ? (4 * tx + j) : (60 + 4 * tx + j);
            CMf[ty * 128 + jl] = cm;
        }
        __syncthreads();
        if (t < 128) {
            float cm = CMf[t];
#pragma unroll
            for (int k = 1; k < 16; ++k) cm = fmaxf(cm, CMf[k * 128 + t]);
            cm = fmaxf(cm, 1e-30f);
            Scol[(bg * NN + (size_t)bj * 128 + t) * 16 + bi] = cm * SK2;
            sinv[t] = 255.f / cm;
        }
        __syncthreads();
#pragma unroll
        for (int i = 0; i < 8; ++i) {
            int m = ((i & 4) << 4) + 4 * ty + (i & 3);
#pragma unroll
            for (int j = 0; j < 8; ++j) {
                int jl = (j < 4) ? (4 * tx + j) : (60 + 4 * tx + j);
                int q = (int)fmaf(acc[i][j], sinv[jl], 0.5f);
                T[jl][m] = (unsigned char)(q > 255 ? 255 : q);
            }
        }
        __syncthreads();
        {
            int r = t >> 1, hf = t & 1;
            size_t grow = (size_t)bz * NN + (size_t)bj * 128 + r;
            unsigned char* dst = Ct + grow * NN + (size_t)bi * 128 + 64 * hf;
            const uint4* src = (const uint4*)&T[r][64 * hf];
            uint4 v0 = src[0], v1 = src[1], v2 = src[2], v3 = src[3];
            *(uint4*)(dst + 0)  = v0;
            *(uint4*)(dst + 16) = v1;
            *(uint4*)(dst + 32) = v2;
            *(uint4*)(dst + 48) = v3;
        }
    }
}

// ---------- Sinkhorn iteration phase (shared by coop + fallback kernels) ----------
struct SArgs {
    const unsigned char *Qxy, *Qyx, *Qxx, *Qyy;   // group-relative [G][2048][2048]
    const float *Sxy, *Syx, *Sxx, *Syy;           // global [NB*NN*16]
    float *Fa, *Gt, *Px, *Py;                     // global [NB*NN]
    float *PaxA, *PaxB, *PayA, *PayB;             // global [NB*NN]
    const float *hx, *hy;                         // global [NB*NN]
    int b0;                                       // batch base of this group
};

// Grid decode: nblk blocks, half 0 = lse pass (f/g), half 1 = sym pass.
// Per half: 2^bshift blocks per batch, (2048>>bshift) rows/block, /4 per wave.
__device__ __forceinline__ void sink_phase(const SArgs& a, int bid, int nblk,
                                           int cur, int ph, float* vs, int bshift) {
    int half = nblk >> 1;
    int mh = bid >= half;
    int rem = mh ? bid - half : bid;
    int brel = rem >> bshift;
    int rb = rem & ((1 << bshift) - 1);
    int rpb = NN >> bshift;            // rows per block
    int rpw = rpb >> 2;                // rows per wave
    int r0 = rb * rpb;
    int t = threadIdx.x;
    int w = t >> 6, l = t & 63;
    size_t bg = (size_t)(a.b0 + brel);
    size_t gx0 = (bg << 11) + r0 + w * rpw;                       // global row base (this wave)
    size_t qbase = ((((size_t)brel << 11) + r0 + w * rpw) << 11); // group-relative Q offset

    const unsigned char* Q;
    const float* S;
    const float* v;
    float* Pa_w = nullptr;
    const float* hp = nullptr;
    float* Pp = nullptr;
    if (ph == 0) {
        if (mh == 0) { Q = a.Qxy; S = a.Sxy; v = a.Gt + (bg << 11); }
        else { Q = a.Qxx; S = a.Sxx; v = (cur ? a.PaxB : a.PaxA) + (bg << 11);
               Pa_w = cur ? a.PaxA : a.PaxB; hp = a.hx; Pp = a.Px; }
    } else {
        if (mh == 0) { Q = a.Qyx; S = a.Syx; v = a.Fa + (bg << 11); }
        else { Q = a.Qyy; S = a.Syy; v = (cur ? a.PayB : a.PayA) + (bg << 11);
               Pa_w = cur ? a.PayA : a.PayB; hp = a.hy; Pp = a.Py; }
    }
    float* out0 = (ph == 0) ? a.Fa : a.Gt;

    // stage v into LDS with XOR swizzle (breaks 128B-stride bank conflict)
    {
        const float4* gv = (const float4*)v;
        float4 a0 = gv[2 * t], a1 = gv[2 * t + 1];
        int B0 = t << 5;
        int sw = ((t >> 2) & 7) << 4;
        *(float4*)((char*)vs + (B0 ^ sw)) = a0;
        *(float4*)((char*)vs + ((B0 + 16) ^ sw)) = a1;
    }
    __syncthreads();
    float vv[32];
#pragma unroll
    for (int u = 0; u < 8; ++u) {
        int B = ((l << 7) + (u << 4)) ^ ((l & 7) << 4);
        *(float4*)&vv[u * 4] = *(const float4*)((char*)vs + B);
    }

    const unsigned char* rp0 = Q + qbase + ((size_t)l << 5);
    uint4 qa = *(const uint4*)rp0;
    uint4 qb = *(const uint4*)(rp0 + 16);
    float sc = S[(gx0 << 4) + (l >> 2)];
#pragma unroll 1
    for (int r = 0; r < rpw; ++r) {
        uint4 na, nb2; float nsc;
        if (r < rpw - 1) {
            const unsigned char* np = rp0 + ((size_t)(r + 1) << 11);
            na = *(const uint4*)np;
            nb2 = *(const uint4*)(np + 16);
            nsc = S[((gx0 + r + 1) << 4) + (l >> 2)];
        }
        unsigned int qs[8] = {qa.x, qa.y, qa.z, qa.w, qb.x, qb.y, qb.z, qb.w};
        float m0 = -INFINITY, m1 = -INFINITY, m2 = -INFINITY, m3 = -INFINITY;
#pragma unroll
        for (int u = 0; u < 8; ++u) {
            unsigned int q = qs[u];
            m0 = fmaxf(m0, fmaf((float)(unsigned char)(q      ), sc, vv[4 * u + 0]));
            m1 = fmaxf(m1, fmaf((float)(unsigned char)(q >>  8), sc, vv[4 * u + 1]));
            m2 = fmaxf(m2, fmaf((float)(unsigned char)(q >> 16), sc, vv[4 * u + 2]));
            m3 = fmaxf(m3, fmaf((float)(q >> 24),                sc, vv[4 * u + 3]));
        }
        float mx = fmaxf(fmaxf(m0, m1), fmaxf(m2, m3));
#pragma unroll
        for (int off = 32; off; off >>= 1) mx = fmaxf(mx, __shfl_xor(mx, off));
        float s0 = 0.f, s1 = 0.f, s2 = 0.f, s3 = 0.f;
#pragma unroll
        for (int u = 0; u < 8; ++u) {
            unsigned int q = qs[u];
            s0 += __builtin_amdgcn_exp2f(fmaf((float)(unsigned char)(q      ), sc, vv[4 * u + 0]) - mx);
            s1 += __builtin_amdgcn_exp2f(fmaf((float)(unsigned char)(q >>  8), sc, vv[4 * u + 1]) - mx);
            s2 += __builtin_amdgcn_exp2f(fmaf((float)(unsigned char)(q >> 16), sc, vv[4 * u + 2]) - mx);
            s3 += __builtin_amdgcn_exp2f(fmaf((float)(q >> 24),                sc, vv[4 * u + 3]) - mx);
        }
        float ss = (s0 + s1) + (s2 + s3);
#pragma unroll
        for (int off = 32; off; off >>= 1) ss += __shfl_xor(ss, off);
        if (l == 0) {
            size_t gx = gx0 + r;
            float lse2 = mx + log2f(ss);
            if (mh == 0) {
                out0[gx] = LNEG2 - lse2;
            } else {
                float pn = 0.5f * (Pp[gx] + hp[gx] - lse2);
                Pp[gx] = pn;
                Pa_w[gx] = LNEG2 + pn - hp[gx];
            }
        }
        qa = na; qb = nb2; sc = nsc;
    }
}

// min-waves/EU = 4 -> VGPR cap 128: the kernel's natural ~64-80 VGPR fits
// WITHOUT spilling (round 7 lesson: forcing 8 squeezed it to 32 and spilled
// the whole row state to scratch -> 13 GB of HBM traffic).
__global__ __launch_bounds__(256, 4) void k_sink(SArgs a, int bshift) {
    cg::grid_group grid = cg::this_grid();
    __shared__ __align__(16) float vs[2048];
    int cur = 0;
    for (int it = 0; it < NITER; ++it) {
        sink_phase(a, blockIdx.x, gridDim.x, cur, 0, vs, bshift);
        grid.sync();
        sink_phase(a, blockIdx.x, gridDim.x, cur, 1, vs, bshift);
        grid.sync();
        cur ^= 1;
    }
}

// Fallback: one phase per launch (inter-launch sync replaces grid.sync)
__global__ __launch_bounds__(256, 4) void k_step(SArgs a, int cur, int ph, int bshift) {
    __shared__ __align__(16) float vs[2048];
    sink_phase(a, blockIdx.x, gridDim.x, cur, ph, vs, bshift);
}

// ---------- final reduction (log2 domain -> natural) ----------
__global__ __launch_bounds__(256) void k_final(const float* __restrict__ Fa, const float* __restrict__ Gt,
                                               const float* __restrict__ Px, const float* __restrict__ Py,
                                               const float* __restrict__ hx, const float* __restrict__ hy,
                                               float* __restrict__ out) {
    int t = threadIdx.x;
    double acc = 0.0;
    for (int i = t; i < NB * NN; i += 256) {
        acc += (double)(Fa[i] + hx[i]) + (double)(Gt[i] + hy[i])
             - (double)Px[i] - (double)Py[i];
    }
    __shared__ double ld[256];
    ld[t] = acc;
    __syncthreads();
    for (int off = 128; off > 0; off >>= 1) {
        if (t < off) ld[t] += ld[t + off];
        __syncthreads();
    }
    if (t == 0) {
        double total = ld[0] - 2.0 * (double)LNEG2 * (double)(NB * NN);
        out[0] = (float)((double)EPS_F * 0.6931471805599453 * total / (double)NN);
    }
}

extern "C" void kernel_launch(void* const* d_in, const int* in_sizes, int n_in,
                              void* d_out, int out_size, void* d_ws, size_t ws_size,
                              hipStream_t stream) {
    (void)in_sizes; (void)n_in; (void)out_size;
    const float* x = (const float*)d_in[0];
    const float* y = (const float*)d_in[1];
    float* out = (float*)d_out;

    char* ws = (char*)d_ws;
    size_t off = 0;
    auto alloc = [&](size_t bytes) -> char* {
        char* p = ws + off;
        off += (bytes + 255) & ~(size_t)255;
        return p;
    };

    float* X2 = (float*)alloc((size_t)NB * NN * ND * 4);
    float* Y2 = (float*)alloc((size_t)NB * NN * ND * 4);
    float* wx = (float*)alloc(ND * 4);
    float* wy = (float*)alloc(ND * 4);
    float* hx = (float*)alloc((size_t)NB * NN * 4);
    float* hy = (float*)alloc((size_t)NB * NN * 4);
    float* Fa = (float*)alloc((size_t)NB * NN * 4);
    float* Gt = (float*)alloc((size_t)NB * NN * 4);
    float* Px = (float*)alloc((size_t)NB * NN * 4);
    float* Py = (float*)alloc((size_t)NB * NN * 4);
    float* PaxA = (float*)alloc((size_t)NB * NN * 4);
    float* PaxB = (float*)alloc((size_t)NB * NN * 4);
    float* PayA = (float*)alloc((size_t)NB * NN * 4);
    float* PayB = (float*)alloc((size_t)NB * NN * 4);
    float* Sxy = (float*)alloc((size_t)NB * NN * 16 * 4);
    float* Syx = (float*)alloc((size_t)NB * NN * 16 * 4);
    float* Sxx = (float*)alloc((size_t)NB * NN * 16 * 4);
    float* Syy = (float*)alloc((size_t)NB * NN * 16 * 4);

    // Q matrices: 4 * 4MB per batch in group; shrink group if workspace is small
    size_t small_end = off;
    size_t matBytes = (size_t)NN * NN;               // 4 MB (u8)
    int G = NB;
    while (G > 1 && small_end + 4 * matBytes * (size_t)G + 4096 > ws_size) G >>= 1;
    unsigned char* Qxy = (unsigned char*)alloc(matBytes * (size_t)G);
    unsigned char* Qyx = (unsigned char*)alloc(matBytes * (size_t)G);
    unsigned char* Qxx = (unsigned char*)alloc(matBytes * (size_t)G);
    unsigned char* Qyy = (unsigned char*)alloc(matBytes * (size_t)G);

    // Size the cooperative grid from the TRUE occupancy of the compiled kernel
    // (host-side queries are deterministic and graph-capture-safe).
    int maxB = 0;
    if (hipOccupancyMaxActiveBlocksPerMultiprocessor(&maxB, reinterpret_cast<const void*>(&k_sink),
                                                     256, 0) != hipSuccess) maxB = 0;
    int ncu = 0;
    if (hipDeviceGetAttribute(&ncu, hipDeviceAttributeMultiprocessorCount, 0) != hipSuccess || ncu <= 0)
        ncu = 256;
    long cap = (long)maxB * (long)ncu;
    int bshift = 5;                                   // 64*G blocks (round-5 baseline)
    while (bshift < 7 && (long)(2 * G << (bshift + 1)) <= cap) ++bshift;
    int nblk = 2 * G << bshift;

    k_colsum<<<dim3(ND, 2), 256, 0, stream>>>(x, y, wx, wy);
    k_norm<<<dim3(NB * NN, 2), 128, 0, stream>>>(x, y, wx, wy, X2, Y2, hx, hy);
    k_init<<<dim3(NB * NN / 256), 256, 0, stream>>>(hx, hy, Gt, Px, PaxA, Py, PayA);

    for (int b0 = 0; b0 < NB; b0 += G) {
        k_gemm<true><<<dim3(16, 16, G), 256, 0, stream>>>(X2, Y2, Sxy, Syx, Qxy, Qyx, b0);
        k_gemm<false><<<dim3(16, 16, G), 256, 0, stream>>>(X2, X2, Sxx, nullptr, Qxx, nullptr, b0);
        k_gemm<false><<<dim3(16, 16, G), 256, 0, stream>>>(Y2, Y2, Syy, nullptr, Qyy, nullptr, b0);

        SArgs sa;
        sa.Qxy = Qxy; sa.Qyx = Qyx; sa.Qxx = Qxx; sa.Qyy = Qyy;
        sa.Sxy = Sxy; sa.Syx = Syx; sa.Sxx = Sxx; sa.Syy = Syy;
        sa.Fa = Fa; sa.Gt = Gt; sa.Px = Px; sa.Py = Py;
        sa.PaxA = PaxA; sa.PaxB = PaxB; sa.PayA = PayA; sa.PayB = PayB;
        sa.hx = hx; sa.hy = hy; sa.b0 = b0;
        void* kargs[] = { &sa, &bshift };
        hipError_t e = hipLaunchCooperativeKernel((void*)k_sink, dim3(nblk), dim3(256),
                                                  kargs, 0, stream);
        if (e != hipSuccess) {
            // fallback: per-phase launches (inter-launch sync replaces grid.sync)
            (void)hipGetLastError();   // clear the error state
            int cur = 0;
            for (int it = 0; it < NITER; ++it) {
                k_step<<<dim3(nblk), 256, 0, stream>>>(sa, cur, 0, bshift);
                k_step<<<dim3(nblk), 256, 0, stream>>>(sa, cur, 1, bshift);
                cur ^= 1;
            }
        }
    }
    k_final<<<dim3(1), 256, 0, stream>>>(Fa, Gt, Px, Py, hx, hy, out);
}

// Round 9
// 1578.394 us; speedup vs baseline: 8.5496x; 3.1024x over previous
//
#include <hip/hip_runtime.h>
#include <math.h>

#define NB 8
#define NN 2048
#define ND 128
#define NITER 32

// eps = blur^2 = (5e-5)^2 = 2.5e-9. All potentials stored in LOG2-scaled units:
// F2 = (f/eps)*log2e etc. M2_ij = dot_ij/eps*log2e = q_ij * S_tile(row).
#define EPS_F   2.5e-9f
#define LNEG2   (-11.0f)                                   /* log2(1/2048) */
#define HSCALE2 ((float)(0.5 * 1.4426950408889634 / 2.5e-9))
#define SK2     ((float)(1.4426950408889634 / (255.0 * 2.5e-9)))

// ---------- preprocessing ----------

// wx[d] = sum_t x[0,t,d]^2  (reference quirk: batch 0 only), same for y
__global__ __launch_bounds__(256) void k_colsum(const float* __restrict__ x,
                                                const float* __restrict__ y,
                                                float* __restrict__ wx,
                                                float* __restrict__ wy) {
    const float* in = blockIdx.y ? y : x;
    float* w = blockIdx.y ? wy : wx;
    int d = blockIdx.x;
    int t = threadIdx.x;
    float sum = 0.f;
    for (int k = t; k < NN; k += 256) {
        float v = in[(size_t)k * ND + d];
        sum += v * v;
    }
    for (int off = 32; off > 0; off >>= 1) sum += __shfl_down(sum, off);
    __shared__ float ls[4];
    if ((t & 63) == 0) ls[t >> 6] = sum;
    __syncthreads();
    if (t == 0) w[d] = ls[0] + ls[1] + ls[2] + ls[3];
}

// X2 = x^2 / wx; h2 = 0.5*|X2 row|^2/eps*log2e
__global__ __launch_bounds__(128) void k_norm(const float* __restrict__ x,
                                              const float* __restrict__ y,
                                              const float* __restrict__ wx,
                                              const float* __restrict__ wy,
                                              float* __restrict__ X2,
                                              float* __restrict__ Y2,
                                              float* __restrict__ hx,
                                              float* __restrict__ hy) {
    int gx = blockIdx.x;                 // b*NN + i
    const float* in = blockIdx.y ? y : x;
    const float* w  = blockIdx.y ? wy : wx;
    float* o  = blockIdx.y ? Y2 : X2;
    float* h  = blockIdx.y ? hy : hx;
    int d = threadIdx.x;
    size_t base = (size_t)gx * ND;
    float v = in[base + d];
    float v2 = (v * v) / w[d];
    o[base + d] = v2;
    float sq = v2 * v2;
    for (int off = 32; off > 0; off >>= 1) sq += __shfl_down(sq, off);
    __shared__ float ls[2];
    if ((d & 63) == 0) ls[d >> 6] = sq;
    __syncthreads();
    if (d == 0) h[gx] = (ls[0] + ls[1]) * HSCALE2;
}

__global__ __launch_bounds__(256) void k_init(const float* __restrict__ hx,
                                              const float* __restrict__ hy,
                                              float* __restrict__ Gt,
                                              float* __restrict__ Px, float* __restrict__ Pax,
                                              float* __restrict__ Py, float* __restrict__ Pay) {
    int tid = blockIdx.x * 256 + threadIdx.x;
    Gt[tid]  = LNEG2 - hy[tid];
    Px[tid]  = 0.f;
    Py[tid]  = 0.f;
    Pax[tid] = LNEG2 - hx[tid];
    Pay[tid] = LNEG2 - hy[tid];
}

__device__ __forceinline__ unsigned int pack4q(const float* a, float iv) {
    int q0 = (int)fmaf(a[0], iv, 0.5f); q0 = q0 > 255 ? 255 : q0;
    int q1 = (int)fmaf(a[1], iv, 0.5f); q1 = q1 > 255 ? 255 : q1;
    int q2 = (int)fmaf(a[2], iv, 0.5f); q2 = q2 > 255 ? 255 : q2;
    int q3 = (int)fmaf(a[3], iv, 0.5f); q3 = q3 > 255 ? 255 : q3;
    return (unsigned int)q0 | ((unsigned int)q1 << 8) | ((unsigned int)q2 << 16) | ((unsigned int)q3 << 24);
}

// ---------- GEMM + per-(row,128-col-tile) max quantization ----------
// LDS: As/Bs (33 KB) reused for the epilogue T/sinv buffers (they are dead
// after the K-loop) -> 33.8 KB total -> 4 blocks/CU.
template<bool DO_T>
__global__ __launch_bounds__(256, 4) void k_gemm(const float* __restrict__ A,
                                                 const float* __restrict__ B,
                                                 float* __restrict__ Srow,
                                                 float* __restrict__ Scol,
                                                 unsigned char* __restrict__ C,
                                                 unsigned char* __restrict__ Ct,
                                                 int b0) {
    __shared__ __align__(16) char smem[33792];
    float (*As)[132] = (float (*)[132])smem;                     // 16896 B
    float (*Bs)[132] = (float (*)[132])(smem + 16896);           // 16896 B
    unsigned char (*T)[144] = (unsigned char (*)[144])smem;      // 18432 B (epilogue)
    float* sinv = (float*)(smem + 18432);                        // 512 B (epilogue)
    int bi = blockIdx.x, bj = blockIdx.y, bz = blockIdx.z;
    size_t bg = (size_t)(b0 + bz);
    const float* Ab = A + (bg * NN + (size_t)bi * 128) * ND;
    const float* Bb = B + (bg * NN + (size_t)bj * 128) * ND;
    int t = threadIdx.x;
    int tx = t & 15, ty = t >> 4;
    float acc[8][8];
#pragma unroll
    for (int i = 0; i < 8; ++i)
#pragma unroll
        for (int j = 0; j < 8; ++j) acc[i][j] = 0.f;
    int lr = t >> 3;            // 0..31
    int kq = (t & 7) << 2;      // k-quad
    for (int kt = 0; kt < ND; kt += 32) {
        __syncthreads();
#pragma unroll
        for (int s2 = 0; s2 < 4; ++s2) {
            int r = lr + (s2 << 5);
            float4 av = *(const float4*)(Ab + (size_t)r * ND + kt + kq);
            As[kq + 0][r] = av.x; As[kq + 1][r] = av.y; As[kq + 2][r] = av.z; As[kq + 3][r] = av.w;
            float4 bv = *(const float4*)(Bb + (size_t)r * ND + kt + kq);
            Bs[kq + 0][r] = bv.x; Bs[kq + 1][r] = bv.y; Bs[kq + 2][r] = bv.z; Bs[kq + 3][r] = bv.w;
        }
        __syncthreads();
#pragma unroll
        for (int k = 0; k < 32; ++k) {
            float a[8], bb[8];
            *(float4*)(a + 0)  = *(const float4*)&As[k][4 * ty];
            *(float4*)(a + 4)  = *(const float4*)&As[k][64 + 4 * ty];
            *(float4*)(bb + 0) = *(const float4*)&Bs[k][4 * tx];
            *(float4*)(bb + 4) = *(const float4*)&Bs[k][64 + 4 * tx];
#pragma unroll
            for (int i = 0; i < 8; ++i)
#pragma unroll
                for (int j = 0; j < 8; ++j)
                    acc[i][j] = fmaf(a[i], bb[j], acc[i][j]);
        }
    }
    // ---- row-tile maxes (shuffle across the 16 tx lanes) + pack pass 1 ----
    float inv_r[8];
#pragma unroll
    for (int i = 0; i < 8; ++i) {
        float m0 = fmaxf(fmaxf(fmaxf(acc[i][0], acc[i][1]), fmaxf(acc[i][2], acc[i][3])),
                         fmaxf(fmaxf(acc[i][4], acc[i][5]), fmaxf(acc[i][6], acc[i][7])));
#pragma unroll
        for (int off = 1; off <= 8; off <<= 1) m0 = fmaxf(m0, __shfl_xor(m0, off));
        m0 = fmaxf(m0, 1e-30f);
        inv_r[i] = 255.f / m0;
        if (tx == 0) {
            int m = ((i & 4) << 4) + 4 * ty + (i & 3);
            Srow[(bg * NN + (size_t)bi * 128 + m) * 16 + bj] = m0 * SK2;
        }
    }
    __syncthreads();        // As/Bs dead from here; T aliases them
#pragma unroll
    for (int i = 0; i < 8; ++i) {
        int m = ((i & 4) << 4) + 4 * ty + (i & 3);
        *(unsigned int*)&T[m][4 * tx]      = pack4q(&acc[i][0], inv_r[i]);
        *(unsigned int*)&T[m][64 + 4 * tx] = pack4q(&acc[i][4], inv_r[i]);
    }
    __syncthreads();
    {
        int r = t >> 1, hf = t & 1;
        size_t grow = (size_t)bz * NN + (size_t)bi * 128 + r;
        unsigned char* dst = C + grow * NN + (size_t)bj * 128 + 64 * hf;
        const uint4* src = (const uint4*)&T[r][64 * hf];
        uint4 v0 = src[0], v1 = src[1], v2 = src[2], v3 = src[3];
        *(uint4*)(dst + 0)  = v0;
        *(uint4*)(dst + 16) = v1;
        *(uint4*)(dst + 32) = v2;
        *(uint4*)(dst + 48) = v3;
    }
    if (DO_T) {
        __syncthreads();                    // T stores consumed; reuse as col-max buffer
        float* CMf = (float*)smem;          // 16 x 128 floats (8 KB)
#pragma unroll
        for (int j = 0; j < 8; ++j) {
            float cm = acc[0][j];
#pragma unroll
            for (int i = 1; i < 8; ++i) cm = fmaxf(cm, acc[i][j]);
            int jl = (j < 4) ? (4 * tx + j) : (60 + 4 * tx + j);
            CMf[ty * 128 + jl] = cm;
        }
        __syncthreads();
        if (t < 128) {
            float cm = CMf[t];
#pragma unroll
            for (int k = 1; k < 16; ++k) cm = fmaxf(cm, CMf[k * 128 + t]);
            cm = fmaxf(cm, 1e-30f);
            Scol[(bg * NN + (size_t)bj * 128 + t) * 16 + bi] = cm * SK2;
            sinv[t] = 255.f / cm;
        }
        __syncthreads();
#pragma unroll
        for (int i = 0; i < 8; ++i) {
            int m = ((i & 4) << 4) + 4 * ty + (i & 3);
#pragma unroll
            for (int j = 0; j < 8; ++j) {
                int jl = (j < 4) ? (4 * tx + j) : (60 + 4 * tx + j);
                int q = (int)fmaf(acc[i][j], sinv[jl], 0.5f);
                T[jl][m] = (unsigned char)(q > 255 ? 255 : q);
            }
        }
        __syncthreads();
        {
            int r = t >> 1, hf = t & 1;
            size_t grow = (size_t)bz * NN + (size_t)bj * 128 + r;
            unsigned char* dst = Ct + grow * NN + (size_t)bi * 128 + 64 * hf;
            const uint4* src = (const uint4*)&T[r][64 * hf];
            uint4 v0 = src[0], v1 = src[1], v2 = src[2], v3 = src[3];
            *(uint4*)(dst + 0)  = v0;
            *(uint4*)(dst + 16) = v1;
            *(uint4*)(dst + 32) = v2;
            *(uint4*)(dst + 48) = v3;
        }
    }
}

// ---------- Sinkhorn iteration phase (one launch per phase; the launch
// boundary IS the grid-wide barrier — round 8 showed cg::grid.sync costs
// ~60+ us per sync at 2048 blocks, dwarfing the ~5 us of work per phase) ----
struct SArgs {
    const unsigned char *Qxy, *Qyx, *Qxx, *Qyy;   // group-relative [G][2048][2048]
    const float *Sxy, *Syx, *Sxx, *Syy;           // global [NB*NN*16]
    float *Fa, *Gt, *Px, *Py;                     // global [NB*NN]
    float *PaxA, *PaxB, *PayA, *PayB;             // global [NB*NN]
    const float *hx, *hy;                         // global [NB*NN]
    int b0;                                       // batch base of this group
};

// Grid decode: nblk blocks, half 0 = lse pass (f/g), half 1 = sym pass.
// Per half: 2^BSHIFT blocks per batch, (2048>>BSHIFT) rows/block, /4 per wave.
#define BSHIFT 7

__global__ __launch_bounds__(256, 4) void k_step(SArgs a, int cur, int ph) {
    __shared__ __align__(16) float vs[2048];
    int nblk = gridDim.x;
    int bid = blockIdx.x;
    int half = nblk >> 1;
    int mh = bid >= half;
    int rem = mh ? bid - half : bid;
    int brel = rem >> BSHIFT;
    int rb = rem & ((1 << BSHIFT) - 1);
    const int rpb = NN >> BSHIFT;      // rows per block
    const int rpw = rpb >> 2;          // rows per wave
    int r0 = rb * rpb;
    int t = threadIdx.x;
    int w = t >> 6, l = t & 63;
    size_t bg = (size_t)(a.b0 + brel);
    size_t gx0 = (bg << 11) + r0 + w * rpw;                       // global row base (this wave)
    size_t qbase = ((((size_t)brel << 11) + r0 + w * rpw) << 11); // group-relative Q offset

    const unsigned char* Q;
    const float* S;
    const float* v;
    float* Pa_w = nullptr;
    const float* hp = nullptr;
    float* Pp = nullptr;
    if (ph == 0) {
        if (mh == 0) { Q = a.Qxy; S = a.Sxy; v = a.Gt + (bg << 11); }
        else { Q = a.Qxx; S = a.Sxx; v = (cur ? a.PaxB : a.PaxA) + (bg << 11);
               Pa_w = cur ? a.PaxA : a.PaxB; hp = a.hx; Pp = a.Px; }
    } else {
        if (mh == 0) { Q = a.Qyx; S = a.Syx; v = a.Fa + (bg << 11); }
        else { Q = a.Qyy; S = a.Syy; v = (cur ? a.PayB : a.PayA) + (bg << 11);
               Pa_w = cur ? a.PayA : a.PayB; hp = a.hy; Pp = a.Py; }
    }
    float* out0 = (ph == 0) ? a.Fa : a.Gt;

    // stage v into LDS with XOR swizzle (breaks 128B-stride bank conflict)
    {
        const float4* gv = (const float4*)v;
        float4 a0 = gv[2 * t], a1 = gv[2 * t + 1];
        int B0 = t << 5;
        int sw = ((t >> 2) & 7) << 4;
        *(float4*)((char*)vs + (B0 ^ sw)) = a0;
        *(float4*)((char*)vs + ((B0 + 16) ^ sw)) = a1;
    }
    __syncthreads();
    float vv[32];
#pragma unroll
    for (int u = 0; u < 8; ++u) {
        int B = ((l << 7) + (u << 4)) ^ ((l & 7) << 4);
        *(float4*)&vv[u * 4] = *(const float4*)((char*)vs + B);
    }

    const unsigned char* rp0 = Q + qbase + ((size_t)l << 5);
    uint4 qa = *(const uint4*)rp0;
    uint4 qb = *(const uint4*)(rp0 + 16);
    float sc = S[(gx0 << 4) + (l >> 2)];
#pragma unroll 1
    for (int r = 0; r < rpw; ++r) {
        uint4 na, nb2; float nsc;
        if (r < rpw - 1) {
            const unsigned char* np = rp0 + ((size_t)(r + 1) << 11);
            na = *(const uint4*)np;
            nb2 = *(const uint4*)(np + 16);
            nsc = S[((gx0 + r + 1) << 4) + (l >> 2)];
        }
        unsigned int qs[8] = {qa.x, qa.y, qa.z, qa.w, qb.x, qb.y, qb.z, qb.w};
        float m0 = -INFINITY, m1 = -INFINITY, m2 = -INFINITY, m3 = -INFINITY;
#pragma unroll
        for (int u = 0; u < 8; ++u) {
            unsigned int q = qs[u];
            m0 = fmaxf(m0, fmaf((float)(unsigned char)(q      ), sc, vv[4 * u + 0]));
            m1 = fmaxf(m1, fmaf((float)(unsigned char)(q >>  8), sc, vv[4 * u + 1]));
            m2 = fmaxf(m2, fmaf((float)(unsigned char)(q >> 16), sc, vv[4 * u + 2]));
            m3 = fmaxf(m3, fmaf((float)(q >> 24),                sc, vv[4 * u + 3]));
        }
        float mx = fmaxf(fmaxf(m0, m1), fmaxf(m2, m3));
#pragma unroll
        for (int off = 32; off; off >>= 1) mx = fmaxf(mx, __shfl_xor(mx, off));
        float s0 = 0.f, s1 = 0.f, s2 = 0.f, s3 = 0.f;
#pragma unroll
        for (int u = 0; u < 8; ++u) {
            unsigned int q = qs[u];
            s0 += __builtin_amdgcn_exp2f(fmaf((float)(unsigned char)(q      ), sc, vv[4 * u + 0]) - mx);
            s1 += __builtin_amdgcn_exp2f(fmaf((float)(unsigned char)(q >>  8), sc, vv[4 * u + 1]) - mx);
            s2 += __builtin_amdgcn_exp2f(fmaf((float)(unsigned char)(q >> 16), sc, vv[4 * u + 2]) - mx);
            s3 += __builtin_amdgcn_exp2f(fmaf((float)(q >> 24),                sc, vv[4 * u + 3]) - mx);
        }
        float ss = (s0 + s1) + (s2 + s3);
#pragma unroll
        for (int off = 32; off; off >>= 1) ss += __shfl_xor(ss, off);
        if (l == 0) {
            size_t gx = gx0 + r;
            float lse2 = mx + log2f(ss);
            if (mh == 0) {
                out0[gx] = LNEG2 - lse2;
            } else {
                float pn = 0.5f * (Pp[gx] + hp[gx] - lse2);
                Pp[gx] = pn;
                Pa_w[gx] = LNEG2 + pn - hp[gx];
            }
        }
        qa = na; qb = nb2; sc = nsc;
    }
}

// ---------- final reduction (log2 domain -> natural) ----------
__global__ __launch_bounds__(256) void k_final(const float* __restrict__ Fa, const float* __restrict__ Gt,
                                               const float* __restrict__ Px, const float* __restrict__ Py,
                                               const float* __restrict__ hx, const float* __restrict__ hy,
                                               float* __restrict__ out) {
    int t = threadIdx.x;
    double acc = 0.0;
    for (int i = t; i < NB * NN; i += 256) {
        acc += (double)(Fa[i] + hx[i]) + (double)(Gt[i] + hy[i])
             - (double)Px[i] - (double)Py[i];
    }
    __shared__ double ld[256];
    ld[t] = acc;
    __syncthreads();
    for (int off = 128; off > 0; off >>= 1) {
        if (t < off) ld[t] += ld[t + off];
        __syncthreads();
    }
    if (t == 0) {
        double total = ld[0] - 2.0 * (double)LNEG2 * (double)(NB * NN);
        out[0] = (float)((double)EPS_F * 0.6931471805599453 * total / (double)NN);
    }
}

extern "C" void kernel_launch(void* const* d_in, const int* in_sizes, int n_in,
                              void* d_out, int out_size, void* d_ws, size_t ws_size,
                              hipStream_t stream) {
    (void)in_sizes; (void)n_in; (void)out_size;
    const float* x = (const float*)d_in[0];
    const float* y = (const float*)d_in[1];
    float* out = (float*)d_out;

    char* ws = (char*)d_ws;
    size_t off = 0;
    auto alloc = [&](size_t bytes) -> char* {
        char* p = ws + off;
        off += (bytes + 255) & ~(size_t)255;
        return p;
    };

    float* X2 = (float*)alloc((size_t)NB * NN * ND * 4);
    float* Y2 = (float*)alloc((size_t)NB * NN * ND * 4);
    float* wx = (float*)alloc(ND * 4);
    float* wy = (float*)alloc(ND * 4);
    float* hx = (float*)alloc((size_t)NB * NN * 4);
    float* hy = (float*)alloc((size_t)NB * NN * 4);
    float* Fa = (float*)alloc((size_t)NB * NN * 4);
    float* Gt = (float*)alloc((size_t)NB * NN * 4);
    float* Px = (float*)alloc((size_t)NB * NN * 4);
    float* Py = (float*)alloc((size_t)NB * NN * 4);
    float* PaxA = (float*)alloc((size_t)NB * NN * 4);
    float* PaxB = (float*)alloc((size_t)NB * NN * 4);
    float* PayA = (float*)alloc((size_t)NB * NN * 4);
    float* PayB = (float*)alloc((size_t)NB * NN * 4);
    float* Sxy = (float*)alloc((size_t)NB * NN * 16 * 4);
    float* Syx = (float*)alloc((size_t)NB * NN * 16 * 4);
    float* Sxx = (float*)alloc((size_t)NB * NN * 16 * 4);
    float* Syy = (float*)alloc((size_t)NB * NN * 16 * 4);

    // Q matrices: 4 * 4MB per batch in group; shrink group if workspace is small
    size_t small_end = off;
    size_t matBytes = (size_t)NN * NN;               // 4 MB (u8)
    int G = NB;
    while (G > 1 && small_end + 4 * matBytes * (size_t)G + 4096 > ws_size) G >>= 1;
    unsigned char* Qxy = (unsigned char*)alloc(matBytes * (size_t)G);
    unsigned char* Qyx = (unsigned char*)alloc(matBytes * (size_t)G);
    unsigned char* Qxx = (unsigned char*)alloc(matBytes * (size_t)G);
    unsigned char* Qyy = (unsigned char*)alloc(matBytes * (size_t)G);

    int nblk = 2 * G << BSHIFT;                      // 2048 blocks at G=8

    k_colsum<<<dim3(ND, 2), 256, 0, stream>>>(x, y, wx, wy);
    k_norm<<<dim3(NB * NN, 2), 128, 0, stream>>>(x, y, wx, wy, X2, Y2, hx, hy);
    k_init<<<dim3(NB * NN / 256), 256, 0, stream>>>(hx, hy, Gt, Px, PaxA, Py, PayA);

    for (int b0 = 0; b0 < NB; b0 += G) {
        k_gemm<true><<<dim3(16, 16, G), 256, 0, stream>>>(X2, Y2, Sxy, Syx, Qxy, Qyx, b0);
        k_gemm<false><<<dim3(16, 16, G), 256, 0, stream>>>(X2, X2, Sxx, nullptr, Qxx, nullptr, b0);
        k_gemm<false><<<dim3(16, 16, G), 256, 0, stream>>>(Y2, Y2, Syy, nullptr, Qyy, nullptr, b0);

        SArgs sa;
        sa.Qxy = Qxy; sa.Qyx = Qyx; sa.Qxx = Qxx; sa.Qyy = Qyy;
        sa.Sxy = Sxy; sa.Syx = Syx; sa.Sxx = Sxx; sa.Syy = Syy;
        sa.Fa = Fa; sa.Gt = Gt; sa.Px = Px; sa.Py = Py;
        sa.PaxA = PaxA; sa.PaxB = PaxB; sa.PayA = PayA; sa.PayB = PayB;
        sa.hx = hx; sa.hy = hy; sa.b0 = b0;

        int cur = 0;
        for (int it = 0; it < NITER; ++it) {
            k_step<<<dim3(nblk), 256, 0, stream>>>(sa, cur, 0);
            k_step<<<dim3(nblk), 256, 0, stream>>>(sa, cur, 1);
            cur ^= 1;
        }
    }
    k_final<<<dim3(1), 256, 0, stream>>>(Fa, Gt, Px, Py, hx, hy, out);
}

// Round 10
// 1408.026 us; speedup vs baseline: 9.5841x; 1.1210x over previous
//
#include <hip/hip_runtime.h>
#include <math.h>

#define NB 8
#define NN 2048
#define ND 128
#define NITER 32

typedef unsigned short ushort_t;
typedef __attribute__((ext_vector_type(8))) short bf16x8;
typedef __attribute__((ext_vector_type(16))) float f32x16;

// eps = blur^2 = (5e-5)^2 = 2.5e-9. All potentials stored in LOG2-scaled units:
// F2 = (f/eps)*log2e etc. M2_ij = dot_ij/eps*log2e = q_ij * S_tile(row).
#define EPS_F   2.5e-9f
#define LNEG2   (-11.0f)                                   /* log2(1/2048) */
#define HSCALE2 ((float)(0.5 * 1.4426950408889634 / 2.5e-9))
#define SK2     ((float)(1.4426950408889634 / (255.0 * 2.5e-9)))

// ---------- preprocessing ----------

// wx[d] = sum_t x[0,t,d]^2  (reference quirk: batch 0 only), same for y
__global__ __launch_bounds__(256) void k_colsum(const float* __restrict__ x,
                                                const float* __restrict__ y,
                                                float* __restrict__ wx,
                                                float* __restrict__ wy) {
    const float* in = blockIdx.y ? y : x;
    float* w = blockIdx.y ? wy : wx;
    int d = blockIdx.x;
    int t = threadIdx.x;
    float sum = 0.f;
    for (int k = t; k < NN; k += 256) {
        float v = in[(size_t)k * ND + d];
        sum += v * v;
    }
    for (int off = 32; off > 0; off >>= 1) sum += __shfl_down(sum, off);
    __shared__ float ls[4];
    if ((t & 63) == 0) ls[t >> 6] = sum;
    __syncthreads();
    if (t == 0) w[d] = ls[0] + ls[1] + ls[2] + ls[3];
}

// v2 = x^2/wx split into bf16 hi + bf16 lo residual; h2 = 0.5*|v2 row|^2/eps*log2e
__global__ __launch_bounds__(128) void k_norm(const float* __restrict__ x,
                                              const float* __restrict__ y,
                                              const float* __restrict__ wx,
                                              const float* __restrict__ wy,
                                              ushort_t* __restrict__ X2h,
                                              ushort_t* __restrict__ X2l,
                                              ushort_t* __restrict__ Y2h,
                                              ushort_t* __restrict__ Y2l,
                                              float* __restrict__ hx,
                                              float* __restrict__ hy) {
    int gx = blockIdx.x;                 // b*NN + i
    const float* in = blockIdx.y ? y : x;
    const float* w  = blockIdx.y ? wy : wx;
    ushort_t* oh = blockIdx.y ? Y2h : X2h;
    ushort_t* ol = blockIdx.y ? Y2l : X2l;
    float* h  = blockIdx.y ? hy : hx;
    int d = threadIdx.x;
    size_t base = (size_t)gx * ND;
    float v = in[base + d];
    float v2 = (v * v) / w[d];
    // RTNE bf16 split: v2 = hi + lo + O(2^-17 * v2)
    unsigned u = __float_as_uint(v2);
    unsigned short hs = (unsigned short)((u + 0x7fffu + ((u >> 16) & 1u)) >> 16);
    float hf = __uint_as_float((unsigned)hs << 16);
    float lo = v2 - hf;
    unsigned ul = __float_as_uint(lo);
    unsigned short lsq = (unsigned short)((ul + 0x7fffu + ((ul >> 16) & 1u)) >> 16);
    oh[base + d] = hs;
    ol[base + d] = lsq;
    float sq = v2 * v2;
    for (int off = 32; off > 0; off >>= 1) sq += __shfl_down(sq, off);
    __shared__ float ls[2];
    if ((d & 63) == 0) ls[d >> 6] = sq;
    __syncthreads();
    if (d == 0) h[gx] = (ls[0] + ls[1]) * HSCALE2;
}

__global__ __launch_bounds__(256) void k_init(const float* __restrict__ hx,
                                              const float* __restrict__ hy,
                                              float* __restrict__ Gt,
                                              float* __restrict__ Px, float* __restrict__ Pax,
                                              float* __restrict__ Py, float* __restrict__ Pay) {
    int tid = blockIdx.x * 256 + threadIdx.x;
    Gt[tid]  = LNEG2 - hy[tid];
    Px[tid]  = 0.f;
    Py[tid]  = 0.f;
    Pax[tid] = LNEG2 - hx[tid];
    Pay[tid] = LNEG2 - hy[tid];
}

// ---------- MFMA GEMM (bf16 hi/lo split) + per-(row,128-col-tile) max u8 quant ----------
// dot = hi*hi + hi*lo + lo*hi  (lo*lo dropped: ~2^-18 relative).
// 128x128 block tile, 4 waves, each wave = 32-row stripe x 4 col-tiles of
// mfma_f32_32x32x16_bf16. C/D layout (m74/m101): col=lane&31,
// row=(reg&3)+8*(reg>>2)+4*(lane>>5). A/B frag: row(col)=lane&31, k=(lane>>5)*8+i.
// TRI variant: symmetric input (xx/yy) -> lower-triangle grid, mirror via DO_T.
template<bool DO_T, bool TRI>
__global__ __launch_bounds__(256, 4) void k_gemm(const ushort_t* __restrict__ Ah,
                                                 const ushort_t* __restrict__ Al,
                                                 const ushort_t* __restrict__ Bh,
                                                 const ushort_t* __restrict__ Bl,
                                                 float* __restrict__ Srow,
                                                 float* __restrict__ Scol,
                                                 unsigned char* __restrict__ C,
                                                 unsigned char* __restrict__ Ct,
                                                 int b0) {
    __shared__ __align__(16) char smem[24576];
    // staging: 4 tiles [128 rows][48 B] (32 bf16 + pad): Ah,Al,Bh,Bl
    // epilogue (aliased): T[128][144] u8 (18432) + sinv 512 + CMf 2048

    int bi, bj, bz;
    if (TRI) {
        int uu = blockIdx.x;
        bi = (int)((sqrtf(8.f * uu + 1.f) - 1.f) * 0.5f);
        bj = uu - bi * (bi + 1) / 2;           // bj <= bi
        bz = blockIdx.y;
    } else {
        bi = blockIdx.x; bj = blockIdx.y; bz = blockIdx.z;
    }
    size_t bg = (size_t)(b0 + bz);
    int t = threadIdx.x;
    int w = t >> 6, l = t & 63;
    int lr = l & 31, hi5 = l >> 5;
    int lk = hi5 * 16;                          // frag k-offset bytes

    f32x16 acc[4];
#pragma unroll
    for (int ct = 0; ct < 4; ++ct)
#pragma unroll
        for (int i = 0; i < 16; ++i) acc[ct][i] = 0.f;

    const int srow = t >> 1;
    const int spart = (t & 1) << 4;             // 0/16 bytes
    const size_t arow0 = (bg * NN + (size_t)bi * 128 + srow) * ND;
    const size_t brow0 = (bg * NN + (size_t)bj * 128 + srow) * ND;

    for (int kt = 0; kt < 8; ++kt) {
        __syncthreads();
        {
            size_t gA = (arow0 + kt * 16 + (t & 1) * 8) * 2;
            size_t gB = (brow0 + kt * 16 + (t & 1) * 8) * 2;
            int ld = srow * 48 + spart;
            *(uint4*)(smem + ld)         = *(const uint4*)((const char*)Ah + gA);
            *(uint4*)(smem + 6144 + ld)  = *(const uint4*)((const char*)Al + gA);
            *(uint4*)(smem + 12288 + ld) = *(const uint4*)((const char*)Bh + gB);
            *(uint4*)(smem + 18432 + ld) = *(const uint4*)((const char*)Bl + gB);
        }
        __syncthreads();
        int ar = (32 * w + lr) * 48 + lk;
        bf16x8 ah = *(const bf16x8*)(smem + ar);
        bf16x8 al = *(const bf16x8*)(smem + 6144 + ar);
#pragma unroll
        for (int ct = 0; ct < 4; ++ct) {
            int br = (32 * ct + lr) * 48 + lk;
            bf16x8 bh = *(const bf16x8*)(smem + 12288 + br);
            bf16x8 bl = *(const bf16x8*)(smem + 18432 + br);
            acc[ct] = __builtin_amdgcn_mfma_f32_32x32x16_bf16(ah, bh, acc[ct], 0, 0, 0);
            acc[ct] = __builtin_amdgcn_mfma_f32_32x32x16_bf16(ah, bl, acc[ct], 0, 0, 0);
            acc[ct] = __builtin_amdgcn_mfma_f32_32x32x16_bf16(al, bh, acc[ct], 0, 0, 0);
        }
    }

    // ---- row maxes (over the block's 128 cols) + scales ----
    float inv_r[16];
#pragma unroll
    for (int r = 0; r < 16; ++r) {
        float m0 = fmaxf(fmaxf(acc[0][r], acc[1][r]), fmaxf(acc[2][r], acc[3][r]));
#pragma unroll
        for (int off = 1; off <= 16; off <<= 1) m0 = fmaxf(m0, __shfl_xor(m0, off));
        m0 = fmaxf(m0, 1e-30f);
        inv_r[r] = 255.f / m0;
        if (lr == 0) {
            int rowblk = (r & 3) + 8 * (r >> 2) + 4 * hi5 + 32 * w;
            Srow[(bg * NN + (size_t)bi * 128 + rowblk) * 16 + bj] = m0 * SK2;
        }
    }
    __syncthreads();            // staging dead; T aliases smem
    unsigned char (*T)[144] = (unsigned char (*)[144])smem;
#pragma unroll
    for (int ct = 0; ct < 4; ++ct)
#pragma unroll
        for (int r = 0; r < 16; ++r) {
            int rowblk = (r & 3) + 8 * (r >> 2) + 4 * hi5 + 32 * w;
            int q = (int)fmaf(acc[ct][r], inv_r[r], 0.5f);
            T[rowblk][ct * 32 + lr] = (unsigned char)(q > 255 ? 255 : q);
        }
    __syncthreads();
    {
        int r2 = t >> 1, hf = t & 1;
        size_t grow = (size_t)bz * NN + (size_t)bi * 128 + r2;
        unsigned char* dst = C + grow * NN + (size_t)bj * 128 + 64 * hf;
        const uint4* src = (const uint4*)&T[r2][64 * hf];
        uint4 v0 = src[0], v1 = src[1], v2 = src[2], v3 = src[3];
        *(uint4*)(dst + 0)  = v0;
        *(uint4*)(dst + 16) = v1;
        *(uint4*)(dst + 32) = v2;
        *(uint4*)(dst + 48) = v3;
    }
    if (DO_T) {
        float* sinv = (float*)(smem + 18432);
        float* CMf  = (float*)(smem + 18944);   // [4][128]
        __syncthreads();                        // pass-1 T reads done
#pragma unroll
        for (int ct = 0; ct < 4; ++ct) {
            float cm = acc[ct][0];
#pragma unroll
            for (int r = 1; r < 16; ++r) cm = fmaxf(cm, acc[ct][r]);
            cm = fmaxf(cm, __shfl_xor(cm, 32));
            if (hi5 == 0) CMf[w * 128 + ct * 32 + lr] = cm;
        }
        __syncthreads();
        if (t < 128) {
            float cm = fmaxf(fmaxf(CMf[t], CMf[128 + t]), fmaxf(CMf[256 + t], CMf[384 + t]));
            cm = fmaxf(cm, 1e-30f);
            Scol[(bg * NN + (size_t)bj * 128 + t) * 16 + bi] = cm * SK2;
            sinv[t] = 255.f / cm;
        }
        __syncthreads();
#pragma unroll
        for (int ct = 0; ct < 4; ++ct) {
            float iv = sinv[ct * 32 + lr];
#pragma unroll
            for (int r = 0; r < 16; ++r) {
                int rowblk = (r & 3) + 8 * (r >> 2) + 4 * hi5 + 32 * w;
                int q = (int)fmaf(acc[ct][r], iv, 0.5f);
                T[ct * 32 + lr][rowblk] = (unsigned char)(q > 255 ? 255 : q);
            }
        }
        __syncthreads();
        {
            int r2 = t >> 1, hf = t & 1;
            size_t grow = (size_t)bz * NN + (size_t)bj * 128 + r2;
            unsigned char* dst = Ct + grow * NN + (size_t)bi * 128 + 64 * hf;
            const uint4* src = (const uint4*)&T[r2][64 * hf];
            uint4 v0 = src[0], v1 = src[1], v2 = src[2], v3 = src[3];
            *(uint4*)(dst + 0)  = v0;
            *(uint4*)(dst + 16) = v1;
            *(uint4*)(dst + 32) = v2;
            *(uint4*)(dst + 48) = v3;
        }
    }
}

// ---------- Sinkhorn iteration phase (one launch per phase; the launch
// boundary IS the grid-wide barrier — r8 showed cg::grid.sync costs ~60 us) ----
struct SArgs {
    const unsigned char *Qxy, *Qyx, *Qxx, *Qyy;   // group-relative [G][2048][2048]
    const float *Sxy, *Syx, *Sxx, *Syy;           // global [NB*NN*16]
    float *Fa, *Gt, *Px, *Py;                     // global [NB*NN]
    float *PaxA, *PaxB, *PayA, *PayB;             // global [NB*NN]
    const float *hx, *hy;                         // global [NB*NN]
    int b0;                                       // batch base of this group
};

#define BSHIFT 7

__global__ __launch_bounds__(256, 4) void k_step(SArgs a, int cur, int ph) {
    __shared__ __align__(16) float vs[2048];
    int nblk = gridDim.x;
    int bid = blockIdx.x;
    int half = nblk >> 1;
    int mh = bid >= half;
    int rem = mh ? bid - half : bid;
    int brel = rem >> BSHIFT;
    int rb = rem & ((1 << BSHIFT) - 1);
    const int rpb = NN >> BSHIFT;      // rows per block
    const int rpw = rpb >> 2;          // rows per wave
    int r0 = rb * rpb;
    int t = threadIdx.x;
    int w = t >> 6, l = t & 63;
    size_t bg = (size_t)(a.b0 + brel);
    size_t gx0 = (bg << 11) + r0 + w * rpw;                       // global row base (this wave)
    size_t qbase = ((((size_t)brel << 11) + r0 + w * rpw) << 11); // group-relative Q offset

    const unsigned char* Q;
    const float* S;
    const float* v;
    float* Pa_w = nullptr;
    const float* hp = nullptr;
    float* Pp = nullptr;
    if (ph == 0) {
        if (mh == 0) { Q = a.Qxy; S = a.Sxy; v = a.Gt + (bg << 11); }
        else { Q = a.Qxx; S = a.Sxx; v = (cur ? a.PaxB : a.PaxA) + (bg << 11);
               Pa_w = cur ? a.PaxA : a.PaxB; hp = a.hx; Pp = a.Px; }
    } else {
        if (mh == 0) { Q = a.Qyx; S = a.Syx; v = a.Fa + (bg << 11); }
        else { Q = a.Qyy; S = a.Syy; v = (cur ? a.PayB : a.PayA) + (bg << 11);
               Pa_w = cur ? a.PayA : a.PayB; hp = a.hy; Pp = a.Py; }
    }
    float* out0 = (ph == 0) ? a.Fa : a.Gt;

    // stage v into LDS with XOR swizzle (breaks 128B-stride bank conflict)
    {
        const float4* gv = (const float4*)v;
        float4 a0 = gv[2 * t], a1 = gv[2 * t + 1];
        int B0 = t << 5;
        int sw = ((t >> 2) & 7) << 4;
        *(float4*)((char*)vs + (B0 ^ sw)) = a0;
        *(float4*)((char*)vs + ((B0 + 16) ^ sw)) = a1;
    }
    __syncthreads();
    float vv[32];
#pragma unroll
    for (int u = 0; u < 8; ++u) {
        int B = ((l << 7) + (u << 4)) ^ ((l & 7) << 4);
        *(float4*)&vv[u * 4] = *(const float4*)((char*)vs + B);
    }

    const unsigned char* rp0 = Q + qbase + ((size_t)l << 5);
    uint4 qa = *(const uint4*)rp0;
    uint4 qb = *(const uint4*)(rp0 + 16);
    float sc = S[(gx0 << 4) + (l >> 2)];
#pragma unroll 1
    for (int r = 0; r < rpw; ++r) {
        uint4 na, nb2; float nsc;
        if (r < rpw - 1) {
            const unsigned char* np = rp0 + ((size_t)(r + 1) << 11);
            na = *(const uint4*)np;
            nb2 = *(const uint4*)(np + 16);
            nsc = S[((gx0 + r + 1) << 4) + (l >> 2)];
        }
        unsigned int qs[8] = {qa.x, qa.y, qa.z, qa.w, qb.x, qb.y, qb.z, qb.w};
        float m0 = -INFINITY, m1 = -INFINITY, m2 = -INFINITY, m3 = -INFINITY;
#pragma unroll
        for (int u = 0; u < 8; ++u) {
            unsigned int q = qs[u];
            m0 = fmaxf(m0, fmaf((float)(unsigned char)(q      ), sc, vv[4 * u + 0]));
            m1 = fmaxf(m1, fmaf((float)(unsigned char)(q >>  8), sc, vv[4 * u + 1]));
            m2 = fmaxf(m2, fmaf((float)(unsigned char)(q >> 16), sc, vv[4 * u + 2]));
            m3 = fmaxf(m3, fmaf((float)(q >> 24),                sc, vv[4 * u + 3]));
        }
        float mx = fmaxf(fmaxf(m0, m1), fmaxf(m2, m3));
#pragma unroll
        for (int off = 32; off; off >>= 1) mx = fmaxf(mx, __shfl_xor(mx, off));
        float s0 = 0.f, s1 = 0.f, s2 = 0.f, s3 = 0.f;
#pragma unroll
        for (int u = 0; u < 8; ++u) {
            unsigned int q = qs[u];
            s0 += __builtin_amdgcn_exp2f(fmaf((float)(unsigned char)(q      ), sc, vv[4 * u + 0]) - mx);
            s1 += __builtin_amdgcn_exp2f(fmaf((float)(unsigned char)(q >>  8), sc, vv[4 * u + 1]) - mx);
            s2 += __builtin_amdgcn_exp2f(fmaf((float)(unsigned char)(q >> 16), sc, vv[4 * u + 2]) - mx);
            s3 += __builtin_amdgcn_exp2f(fmaf((float)(q >> 24),                sc, vv[4 * u + 3]) - mx);
        }
        float ss = (s0 + s1) + (s2 + s3);
#pragma unroll
        for (int off = 32; off; off >>= 1) ss += __shfl_xor(ss, off);
        if (l == 0) {
            size_t gx = gx0 + r;
            float lse2 = mx + log2f(ss);
            if (mh == 0) {
                out0[gx] = LNEG2 - lse2;
            } else {
                float pn = 0.5f * (Pp[gx] + hp[gx] - lse2);
                Pp[gx] = pn;
                Pa_w[gx] = LNEG2 + pn - hp[gx];
            }
        }
        qa = na; qb = nb2; sc = nsc;
    }
}

// ---------- final reduction (log2 domain -> natural) ----------
__global__ __launch_bounds__(256) void k_final(const float* __restrict__ Fa, const float* __restrict__ Gt,
                                               const float* __restrict__ Px, const float* __restrict__ Py,
                                               const float* __restrict__ hx, const float* __restrict__ hy,
                                               float* __restrict__ out) {
    int t = threadIdx.x;
    double acc = 0.0;
    for (int i = t; i < NB * NN; i += 256) {
        acc += (double)(Fa[i] + hx[i]) + (double)(Gt[i] + hy[i])
             - (double)Px[i] - (double)Py[i];
    }
    __shared__ double ld[256];
    ld[t] = acc;
    __syncthreads();
    for (int off = 128; off > 0; off >>= 1) {
        if (t < off) ld[t] += ld[t + off];
        __syncthreads();
    }
    if (t == 0) {
        double total = ld[0] - 2.0 * (double)LNEG2 * (double)(NB * NN);
        out[0] = (float)((double)EPS_F * 0.6931471805599453 * total / (double)NN);
    }
}

extern "C" void kernel_launch(void* const* d_in, const int* in_sizes, int n_in,
                              void* d_out, int out_size, void* d_ws, size_t ws_size,
                              hipStream_t stream) {
    (void)in_sizes; (void)n_in; (void)out_size;
    const float* x = (const float*)d_in[0];
    const float* y = (const float*)d_in[1];
    float* out = (float*)d_out;

    char* ws = (char*)d_ws;
    size_t off = 0;
    auto alloc = [&](size_t bytes) -> char* {
        char* p = ws + off;
        off += (bytes + 255) & ~(size_t)255;
        return p;
    };

    ushort_t* X2h = (ushort_t*)alloc((size_t)NB * NN * ND * 2);
    ushort_t* X2l = (ushort_t*)alloc((size_t)NB * NN * ND * 2);
    ushort_t* Y2h = (ushort_t*)alloc((size_t)NB * NN * ND * 2);
    ushort_t* Y2l = (ushort_t*)alloc((size_t)NB * NN * ND * 2);
    float* wx = (float*)alloc(ND * 4);
    float* wy = (float*)alloc(ND * 4);
    float* hx = (float*)alloc((size_t)NB * NN * 4);
    float* hy = (float*)alloc((size_t)NB * NN * 4);
    float* Fa = (float*)alloc((size_t)NB * NN * 4);
    float* Gt = (float*)alloc((size_t)NB * NN * 4);
    float* Px = (float*)alloc((size_t)NB * NN * 4);
    float* Py = (float*)alloc((size_t)NB * NN * 4);
    float* PaxA = (float*)alloc((size_t)NB * NN * 4);
    float* PaxB = (float*)alloc((size_t)NB * NN * 4);
    float* PayA = (float*)alloc((size_t)NB * NN * 4);
    float* PayB = (float*)alloc((size_t)NB * NN * 4);
    float* Sxy = (float*)alloc((size_t)NB * NN * 16 * 4);
    float* Syx = (float*)alloc((size_t)NB * NN * 16 * 4);
    float* Sxx = (float*)alloc((size_t)NB * NN * 16 * 4);
    float* Syy = (float*)alloc((size_t)NB * NN * 16 * 4);

    // Q matrices: 4 * 4MB per batch in group; shrink group if workspace is small
    size_t small_end = off;
    size_t matBytes = (size_t)NN * NN;               // 4 MB (u8)
    int G = NB;
    while (G > 1 && small_end + 4 * matBytes * (size_t)G + 4096 > ws_size) G >>= 1;
    unsigned char* Qxy = (unsigned char*)alloc(matBytes * (size_t)G);
    unsigned char* Qyx = (unsigned char*)alloc(matBytes * (size_t)G);
    unsigned char* Qxx = (unsigned char*)alloc(matBytes * (size_t)G);
    unsigned char* Qyy = (unsigned char*)alloc(matBytes * (size_t)G);

    int nblk = 2 * G << BSHIFT;                      // 2048 blocks at G=8

    k_colsum<<<dim3(ND, 2), 256, 0, stream>>>(x, y, wx, wy);
    k_norm<<<dim3(NB * NN, 2), 128, 0, stream>>>(x, y, wx, wy, X2h, X2l, Y2h, Y2l, hx, hy);
    k_init<<<dim3(NB * NN / 256), 256, 0, stream>>>(hx, hy, Gt, Px, PaxA, Py, PayA);

    for (int b0 = 0; b0 < NB; b0 += G) {
        // xy: full grid, emits Qxy (row-scaled) + Qyx (transposed, col-scaled)
        k_gemm<true, false><<<dim3(16, 16, G), 256, 0, stream>>>(
            X2h, X2l, Y2h, Y2l, Sxy, Syx, Qxy, Qyx, b0);
        // xx/yy: symmetric -> lower-triangle grid; DO_T mirrors into upper half
        k_gemm<true, true><<<dim3(136, G), 256, 0, stream>>>(
            X2h, X2l, X2h, X2l, Sxx, Sxx, Qxx, Qxx, b0);
        k_gemm<true, true><<<dim3(136, G), 256, 0, stream>>>(
            Y2h, Y2l, Y2h, Y2l, Syy, Syy, Qyy, Qyy, b0);

        SArgs sa;
        sa.Qxy = Qxy; sa.Qyx = Qyx; sa.Qxx = Qxx; sa.Qyy = Qyy;
        sa.Sxy = Sxy; sa.Syx = Syx; sa.Sxx = Sxx; sa.Syy = Syy;
        sa.Fa = Fa; sa.Gt = Gt; sa.Px = Px; sa.Py = Py;
        sa.PaxA = PaxA; sa.PaxB = PaxB; sa.PayA = PayA; sa.PayB = PayB;
        sa.hx = hx; sa.hy = hy; sa.b0 = b0;

        int cur = 0;
        for (int it = 0; it < NITER; ++it) {
            k_step<<<dim3(nblk), 256, 0, stream>>>(sa, cur, 0);
            k_step<<<dim3(nblk), 256, 0, stream>>>(sa, cur, 1);
            cur ^= 1;
        }
    }
    k_final<<<dim3(1), 256, 0, stream>>>(Fa, Gt, Px, Py, hx, hy, out);
}